// Round 13
// baseline (205.461 us; speedup 1.0000x reference)
//
#include <hip/hip_runtime.h>
#include <hip/hip_bf16.h>
#include <stdint.h>

typedef __bf16 bf16;
typedef __attribute__((ext_vector_type(8))) __bf16 bf16x8;
typedef __attribute__((ext_vector_type(4))) float f32x4;
typedef __attribute__((ext_vector_type(8))) unsigned short u16x8;

#define LDS_U32 __attribute__((address_space(3))) uint32_t
#define GLB_U32 const __attribute__((address_space(1))) uint32_t
#define GLOAD16(g, l) __builtin_amdgcn_global_load_lds((GLB_U32*)(g), (LDS_U32*)(l), 16, 0, 0)

#define DSR(dst, addr, OFFLIT) \
  asm volatile("ds_read_b128 %0, %1 offset:" OFFLIT : "=v"(dst) : "v"(addr))

#define WAIT_LGKM0() asm volatile("s_waitcnt lgkmcnt(0)")
#define WAIT_LGKM4() asm volatile("s_waitcnt lgkmcnt(4)")
#define WAIT_VM0()   asm volatile("s_waitcnt vmcnt(0)")
#define SB()         __builtin_amdgcn_sched_barrier(0)

// ---------------- fused f32 -> bf16 convert (all 5 inputs, one launch) ----------------
__global__ __launch_bounds__(256) void cvt_all(const float* __restrict__ q,
                                               const float* __restrict__ wq,
                                               const float* __restrict__ wk,
                                               const float* __restrict__ wv,
                                               const float* __restrict__ wo,
                                               bf16* __restrict__ qb,
                                               bf16* __restrict__ W3,
                                               bf16* __restrict__ wob) {
  const int b = blockIdx.x;
  const float* src;
  bf16* dst;
  int within;
  if (b < 2048) { src = q; dst = qb; within = b; }
  else {
    const int seg = (b - 2048) >> 8;      // 0..3
    within = (b - 2048) & 255;
    if (seg == 0)      { src = wq; dst = W3; }
    else if (seg == 1) { src = wk; dst = W3 + 1048576; }
    else if (seg == 2) { src = wv; dst = W3 + 2097152; }
    else               { src = wo; dst = wob; }
  }
  const int off = within * 1024;
#pragma unroll
  for (int it = 0; it < 4; ++it) {
    const int j = off + it * 256 + threadIdx.x;
    float4 v = reinterpret_cast<const float4*>(src)[j];
    ushort4 o;
    o.x = __builtin_bit_cast(unsigned short, (bf16)v.x);
    o.y = __builtin_bit_cast(unsigned short, (bf16)v.y);
    o.z = __builtin_bit_cast(unsigned short, (bf16)v.z);
    o.w = __builtin_bit_cast(unsigned short, (bf16)v.w);
    reinterpret_cast<ushort4*>(dst)[j] = o;
  }
}

// ============ 256 x (WN*64) double-buffered GEMM, C = alpha * A @ B^T ============
// r13: intra-phase counted-lgkm software pipeline. r12's {issue all reads ->
// lgkmcnt(0) drain -> MFMA burst} left ~200+ dead cycles per phase (all 8
// waves lockstepped). Now: issue reads for TWO quads, wait lgkmcnt(4) (first
// batch done, second in flight), MFMA quad q while quad q+1's reads return —
// the m97-compiler / m201-manual interleave, restored around the asm DSRs.
// sched_barrier(0) after every wait (rule #18: MFMA hoisting past bare asm).
// Staging of T+1 is fully front-loaded at K-tile top (max HBM-latency cover
// before the boundary vmcnt(0); WAR-safe: target parity's readers finished at
// the previous boundary barrier). One s_barrier per K-tile.
// LDS per parity: A 32KB (4 units x 8KB, 64 rows x 64k) + B WN*8KB;
// PARB = 32768 + WN*8192; 2 parities. st_16x32 swizzle both sides.
// EPI: 0 = bf16 C[z*sC+r*ldc+c]; 2 = f32 C[r*ldc+c];
//      4 = Vt scatter: Vt[(r>>11)*2097152 + c*2048 + (r&2047)];
//      5 = QK route: c<1024 -> Qb[r*1024+c], else Kb[r*1024+c-1024].
template <int EPI, int WN>
__global__ __launch_bounds__(512, 2) void g256(const bf16* __restrict__ A,
                                               const bf16* __restrict__ Bm,
                                               void* __restrict__ Cp,
                                               int K, float alpha,
                                               long sA, long sB, long sC, int ldc) {
  constexpr int BN = WN * 64;
  constexpr uint32_t PARB = 32768u + WN * 8192u;  // parity stride in bytes
  __shared__ bf16 smem_[PARB];                    // 2 parities x PARB bytes
  const long z = blockIdx.z;
  const int t = threadIdx.x;
  const int l = t & 63;
  const int w = t >> 6;
  const int wr = (w >> 2) * 128;        // wave row base within 256
  const int wc = (w & 3) * (WN * 16);   // wave col base within BN
  const int NT = K >> 6;

  const bf16* Ab = A + z * sA + (long)(blockIdx.y * 256) * K;
  const bf16* Bb = Bm + z * sB + (long)(blockIdx.x * BN) * K;

  // staging inverse map: thread t covers swizzled bytes [t*16, t*16+16) of one
  // 8KB 64-row unit; (r0,c0) = source row/col within the unit.
  uint32_t loc = (uint32_t)t * 16u;
  uint32_t g0 = loc ^ (((loc >> 9) & 1u) << 5);
  const int r0 = (int)(((g0 >> 10) >> 1) * 16 + ((g0 >> 6) & 15));  // 0..63
  const int c0 = (int)(((g0 >> 10) & 1) * 32 + ((g0 & 63) >> 1));   // 0..63

  // per-lane swizzled fragment read offset
  uint32_t lo_ = (uint32_t)((l & 15) * 64 + (l >> 4) * 16);
  const uint32_t lane_off = lo_ ^ (((lo_ >> 9) & 1u) << 5);
  const uint32_t aRegion = (uint32_t)(wr >> 7) * 16384u;
  const uint32_t smem_base = (uint32_t)(size_t)&smem_[0];
  const uint32_t aBase = smem_base + aRegion + lane_off;  // + parity + quad*4096

  // per-n B fragment base addresses (row = wc + n*16 within B panel)
  uint32_t bA[WN];
#pragma unroll
  for (int n = 0; n < WN; ++n) {
    const uint32_t row = (uint32_t)(wc + n * 16);
    bA[n] = smem_base + 32768u + (row >> 6) * 8192u + ((row & 63u) >> 4) * 2048u + lane_off;
  }

  // stage one 64-row unit of tile `tile` into parity (tile&1)
  auto STAGE1 = [&](const bf16* mat, int unit, int tile, uint32_t isB) {
    uint32_t dst = (uint32_t)(tile & 1) * PARB + isB + (uint32_t)unit * 8192u + (uint32_t)t * 16u;
    const bf16* src = mat + (long)(unit * 64 + r0) * K + tile * 64 + c0;
    GLOAD16(src, smem_ + (dst >> 1));
  };

  f32x4 acc[8][WN] = {};

  // ---- prologue: A(0) + B(0) into parity 0
  STAGE1(Ab, 0, 0, 0u); STAGE1(Ab, 1, 0, 0u); STAGE1(Ab, 2, 0, 0u); STAGE1(Ab, 3, 0, 0u);
#pragma unroll
  for (int u = 0; u < WN; ++u) STAGE1(Bb, u, 0, 32768u);
  SB();
  WAIT_VM0();
  __builtin_amdgcn_s_barrier();

  // MFMA for output quad Q (acc rows Q*2, Q*2+1) using aF slot S
#define MFMAQ(Q, S)                                                                  \
  _Pragma("unroll") for (int mi = 0; mi < 2; ++mi)                                   \
  _Pragma("unroll") for (int n = 0; n < WN; ++n)                                     \
  _Pragma("unroll") for (int kk = 0; kk < 2; ++kk)                                   \
    acc[(Q) * 2 + mi][n] = __builtin_amdgcn_mfma_f32_16x16x32_bf16(                  \
        __builtin_bit_cast(bf16x8, aF[S][mi][kk]), __builtin_bit_cast(bf16x8, bF[n][kk]), \
        acc[(Q) * 2 + mi][n], 0, 0, 0);

  for (int T = 0; T < NT; ++T) {
    const uint32_t pb = (uint32_t)(T & 1) * PARB;
    const uint32_t aA = aBase + pb;
    f32x4 bF[WN][2];
    f32x4 aF[2][2][2];  // [slot][mi][kk]

    // ---- front-load ALL staging of tile T+1 (other parity; WAR-safe) ----
    if (T + 1 < NT) {
#pragma unroll
      for (int u = 0; u < WN; ++u) STAGE1(Bb, u, T + 1, 32768u);
      STAGE1(Ab, 0, T + 1, 0u); STAGE1(Ab, 1, T + 1, 0u);
      STAGE1(Ab, 2, T + 1, 0u); STAGE1(Ab, 3, T + 1, 0u);
    }

    // ---- phase A: issue bF(2WN) + aF q0(4) + q1(4) ----
#pragma unroll
    for (int n = 0; n < WN; ++n) {
      DSR(bF[n][0], bA[n] + pb, "0");
      DSR(bF[n][1], bA[n] + pb, "1024");
    }
    DSR(aF[0][0][0], aA, "0");    DSR(aF[0][0][1], aA, "1024");
    DSR(aF[0][1][0], aA, "2048"); DSR(aF[0][1][1], aA, "3072");
    DSR(aF[1][0][0], aA, "4096"); DSR(aF[1][0][1], aA, "5120");
    DSR(aF[1][1][0], aA, "6144"); DSR(aF[1][1][1], aA, "7168");
    SB();
    WAIT_LGKM4();   // bF + q0 landed; q1 (4 reads) in flight
    SB();
    __builtin_amdgcn_s_setprio(1);
    MFMAQ(0, 0)     // hides q1's return latency
    __builtin_amdgcn_s_setprio(0);
    SB();
    WAIT_LGKM0();   // q1 landed
    SB();
    __builtin_amdgcn_s_setprio(1);
    MFMAQ(1, 1)
    __builtin_amdgcn_s_setprio(0);
    SB();

    // ---- phase B: issue aF q2(4) + q3(4), reuse slots ----
    DSR(aF[0][0][0], aA, "8192");  DSR(aF[0][0][1], aA, "9216");
    DSR(aF[0][1][0], aA, "10240"); DSR(aF[0][1][1], aA, "11264");
    DSR(aF[1][0][0], aA, "12288"); DSR(aF[1][0][1], aA, "13312");
    DSR(aF[1][1][0], aA, "14336"); DSR(aF[1][1][1], aA, "15360");
    SB();
    WAIT_LGKM4();   // q2 landed; q3 in flight
    SB();
    __builtin_amdgcn_s_setprio(1);
    MFMAQ(2, 0)
    __builtin_amdgcn_s_setprio(0);
    SB();
    WAIT_LGKM0();   // q3 landed
    SB();
    __builtin_amdgcn_s_setprio(1);
    MFMAQ(3, 1)
    __builtin_amdgcn_s_setprio(0);
    SB();

    // ---- boundary: T+1 stages landed & visible to all waves ----
    WAIT_VM0();
    __builtin_amdgcn_s_barrier();
  }
#undef MFMAQ

  // ---- epilogue: C/D layout col = lane&15, row = (lane>>4)*4 + i
  const int orow0 = blockIdx.y * 256 + wr + (l >> 4) * 4;
  const int ocol0 = blockIdx.x * BN + wc + (l & 15);
#pragma unroll
  for (int m = 0; m < 8; ++m)
#pragma unroll
    for (int n = 0; n < WN; ++n)
#pragma unroll
      for (int i = 0; i < 4; ++i) {
        const long r = orow0 + m * 16 + i;
        const long c = ocol0 + n * 16;
        const float v = acc[m][n][i] * alpha;
        if constexpr (EPI == 0) {
          ((bf16*)Cp)[z * sC + r * ldc + c] = (bf16)v;
        } else if constexpr (EPI == 2) {
          ((float*)Cp)[r * ldc + c] = v;
        } else if constexpr (EPI == 4) {
          // V-proj -> Vt[b][e][s]: r = b*2048+s, c = e
          ((bf16*)Cp)[(r >> 11) * 2097152 + c * 2048 + (r & 2047)] = (bf16)v;
        } else {
          // QK-proj route: c<1024 -> Q, else K  (rows r = b*2048+s)
          bf16* Qb = (bf16*)Cp;
          bf16* Kb = Qb + 8388608;  // 8192*1024
          if (c < 1024) Qb[r * 1024 + c] = (bf16)v;
          else Kb[r * 1024 + (c - 1024)] = (bf16)v;
        }
      }
}

// ---------------- row softmax, in place, rows of 2048 bf16 ----------------
__global__ __launch_bounds__(256) void softmax_rows(bf16* __restrict__ P) {
  const long row = blockIdx.x;
  bf16* p = P + row * 2048;
  const int t = threadIdx.x;
  const int lane = t & 63;
  const int wave = t >> 6;

  u16x8 raw = *reinterpret_cast<const u16x8*>(p + t * 8);
  float v[8];
#pragma unroll
  for (int j = 0; j < 8; ++j) {
    uint32_t bits = ((uint32_t)raw[j]) << 16;
    v[j] = __builtin_bit_cast(float, bits);
  }
  float m = v[0];
#pragma unroll
  for (int j = 1; j < 8; ++j) m = fmaxf(m, v[j]);
#pragma unroll
  for (int off = 32; off > 0; off >>= 1) m = fmaxf(m, __shfl_xor(m, off, 64));
  __shared__ float redm[4];
  __shared__ float reds[4];
  if (lane == 0) redm[wave] = m;
  __syncthreads();
  m = fmaxf(fmaxf(redm[0], redm[1]), fmaxf(redm[2], redm[3]));

  float s = 0.f;
#pragma unroll
  for (int j = 0; j < 8; ++j) {
    v[j] = __expf(v[j] - m);
    s += v[j];
  }
#pragma unroll
  for (int off = 32; off > 0; off >>= 1) s += __shfl_xor(s, off, 64);
  if (lane == 0) reds[wave] = s;
  __syncthreads();
  s = reds[0] + reds[1] + reds[2] + reds[3];
  const float inv = 1.f / s;

  u16x8 o;
#pragma unroll
  for (int j = 0; j < 8; ++j) o[j] = __builtin_bit_cast(unsigned short, (bf16)(v[j] * inv));
  *reinterpret_cast<u16x8*>(p + t * 8) = o;
}

// ---------------- launch ----------------
extern "C" void kernel_launch(void* const* d_in, const int* in_sizes, int n_in,
                              void* d_out, int out_size, void* d_ws, size_t ws_size,
                              hipStream_t stream) {
  const float* q = (const float*)d_in[0];
  const float* wq = (const float*)d_in[1];
  const float* wk = (const float*)d_in[2];
  const float* wv = (const float*)d_in[3];
  const float* wo = (const float*)d_in[4];
  float* out = (float*)d_out;

  constexpr int B = 4, S = 2048, D = 1024;
  constexpr long SD = (long)S * D;  // 2,097,152
  constexpr long SS = (long)S * S;  // 4,194,304
  constexpr long DD = (long)D * D;  // 1,048,576

  bf16* wsb = (bf16*)d_ws;
  bf16* qb = wsb;             // B*SD
  bf16* W3 = qb + B * SD;     // 3*DD  (wq;wk;wv stacked rows)
  bf16* wob = W3 + 3 * DD;    // DD
  bf16* Qb = wob + DD;        // B*SD
  bf16* Kb = Qb + B * SD;     // B*SD
  bf16* Vt = Kb + B * SD;     // B*SD, layout [B][D][S]
  bf16* P = Vt + B * SD;      // B*SS
  bf16* X = P + B * SS;       // B*SD, layout [B][D][S] == bugged buffer

  cvt_all<<<3072, 256, 0, stream>>>(q, wq, wk, wv, wo, qb, W3, wob);

  // QK-proj: [8192x1024] @ [2048x1024]^T -> Qb,Kb. WN=4, 256 blocks = 1/CU.
  g256<5, 4><<<dim3(8, 32, 1), 512, 0, stream>>>(qb, W3, Qb, D, 1.f, 0, 0, 0, 0);
  // V-proj: [8192x1024] @ [1024x1024]^T -> Vt (transposed). WN=2, 256 blocks.
  g256<4, 2><<<dim3(8, 32, 1), 512, 0, stream>>>(qb, W3 + 2 * DD, Vt, D, 1.f, 0, 0, 0, 0);
  // scores: P[b][i][j] = Q.K/8  (per batch 2048x2048, K=1024), 256 blocks = 1/CU
  g256<0, 4><<<dim3(8, 8, B), 512, 0, stream>>>(Qb, Kb, P, D, 0.125f, SD, SD, SS, S);
  softmax_rows<<<B * S, 256, 0, stream>>>(P);
  // PV as Xt = Vt @ P^T (M=1024, N=2048, K=2048): 256x128 tile, 256 blocks = 1/CU
  g256<0, 2><<<dim3(16, 4, B), 512, 0, stream>>>(Vt, P, X, S, 1.f, SD, SS, SD, S);
  // out = Xflat[8192x1024] @ wo^T -> f32: 256x128, 256 blocks = 1/CU
  g256<2, 2><<<dim3(8, 32, 1), 512, 0, stream>>>(X, wob, out, D, 1.f, 0, 0, 0, D);
}

// Round 14
// 205.329 us; speedup vs baseline: 1.0006x; 1.0006x over previous
//
#include <hip/hip_runtime.h>
#include <hip/hip_bf16.h>
#include <stdint.h>

typedef __bf16 bf16;
typedef __attribute__((ext_vector_type(8))) __bf16 bf16x8;
typedef __attribute__((ext_vector_type(4))) float f32x4;
typedef __attribute__((ext_vector_type(8))) unsigned short u16x8;

#define LDS_U32 __attribute__((address_space(3))) uint32_t
#define GLB_U32 const __attribute__((address_space(1))) uint32_t
#define GLOAD16(g, l) __builtin_amdgcn_global_load_lds((GLB_U32*)(g), (LDS_U32*)(l), 16, 0, 0)

#define DSR(dst, addr, OFFLIT) \
  asm volatile("ds_read_b128 %0, %1 offset:" OFFLIT : "=v"(dst) : "v"(addr))

#define WAIT_LGKM0() asm volatile("s_waitcnt lgkmcnt(0)")
#define WAIT_LGKM4() asm volatile("s_waitcnt lgkmcnt(4)")
#define WAIT_VM0()   asm volatile("s_waitcnt vmcnt(0)")
#define SB()         __builtin_amdgcn_sched_barrier(0)

// ---------------- fused f32 -> bf16 convert (all 5 inputs, one launch) ----------------
__global__ __launch_bounds__(256) void cvt_all(const float* __restrict__ q,
                                               const float* __restrict__ wq,
                                               const float* __restrict__ wk,
                                               const float* __restrict__ wv,
                                               const float* __restrict__ wo,
                                               bf16* __restrict__ qb,
                                               bf16* __restrict__ W3,
                                               bf16* __restrict__ wob) {
  const int b = blockIdx.x;
  const float* src;
  bf16* dst;
  int within;
  if (b < 2048) { src = q; dst = qb; within = b; }
  else {
    const int seg = (b - 2048) >> 8;      // 0..3
    within = (b - 2048) & 255;
    if (seg == 0)      { src = wq; dst = W3; }
    else if (seg == 1) { src = wk; dst = W3 + 1048576; }
    else if (seg == 2) { src = wv; dst = W3 + 2097152; }
    else               { src = wo; dst = wob; }
  }
  const int off = within * 1024;
#pragma unroll
  for (int it = 0; it < 4; ++it) {
    const int j = off + it * 256 + threadIdx.x;
    float4 v = reinterpret_cast<const float4*>(src)[j];
    ushort4 o;
    o.x = __builtin_bit_cast(unsigned short, (bf16)v.x);
    o.y = __builtin_bit_cast(unsigned short, (bf16)v.y);
    o.z = __builtin_bit_cast(unsigned short, (bf16)v.z);
    o.w = __builtin_bit_cast(unsigned short, (bf16)v.w);
    reinterpret_cast<ushort4*>(dst)[j] = o;
  }
}

// ============ 256 x (WN*64) double-buffered GEMM, C = alpha * A @ B^T ============
// r14: SCHED_BARRIER ABLATION. r13's SB(0) after every wait/stage pinned the
// instruction order and defeated the compiler scheduler — the exact m141
// mechanism (874->510 TF, 1.7x). The volatile-asm DSR/WAIT chain is already
// mutually ordered, so SBs are kept ONLY where required:
//   - after each lgkm-wait (rule #18: register-only MFMA hoists above bare
//     inline-asm waitcnt; the SB is the fence),
//   - before each vmcnt boundary (global_load_lds intrinsics CAN sink below
//     bare volatile asm; SB pins them above the count-wait).
// Everything else (MFMA sinking into next DSR-issue window, stage floating
// under compute, address VALU motion) is now free for the scheduler.
// Structure otherwise = r13: LDS parity double-buffer (PARB = 32KB + WN*8KB),
// T+1 staging front-loaded at tile top (WAR-free: other parity), counted
// lgkm(4) intra-phase pipeline, ONE s_barrier per K-tile, st_16x32 swizzle.
// EPI: 0 = bf16 C[z*sC+r*ldc+c]; 2 = f32 C[r*ldc+c];
//      4 = Vt scatter: Vt[(r>>11)*2097152 + c*2048 + (r&2047)];
//      5 = QK route: c<1024 -> Qb[r*1024+c], else Kb[r*1024+c-1024].
template <int EPI, int WN>
__global__ __launch_bounds__(512, 2) void g256(const bf16* __restrict__ A,
                                               const bf16* __restrict__ Bm,
                                               void* __restrict__ Cp,
                                               int K, float alpha,
                                               long sA, long sB, long sC, int ldc) {
  constexpr int BN = WN * 64;
  constexpr uint32_t PARB = 32768u + WN * 8192u;  // parity stride in bytes
  __shared__ bf16 smem_[PARB];                    // 2 parities x PARB bytes
  const long z = blockIdx.z;
  const int t = threadIdx.x;
  const int l = t & 63;
  const int w = t >> 6;
  const int wr = (w >> 2) * 128;        // wave row base within 256
  const int wc = (w & 3) * (WN * 16);   // wave col base within BN
  const int NT = K >> 6;

  const bf16* Ab = A + z * sA + (long)(blockIdx.y * 256) * K;
  const bf16* Bb = Bm + z * sB + (long)(blockIdx.x * BN) * K;

  // staging inverse map: thread t covers swizzled bytes [t*16, t*16+16) of one
  // 8KB 64-row unit; (r0,c0) = source row/col within the unit.
  uint32_t loc = (uint32_t)t * 16u;
  uint32_t g0 = loc ^ (((loc >> 9) & 1u) << 5);
  const int r0 = (int)(((g0 >> 10) >> 1) * 16 + ((g0 >> 6) & 15));  // 0..63
  const int c0 = (int)(((g0 >> 10) & 1) * 32 + ((g0 & 63) >> 1));   // 0..63

  // per-lane swizzled fragment read offset
  uint32_t lo_ = (uint32_t)((l & 15) * 64 + (l >> 4) * 16);
  const uint32_t lane_off = lo_ ^ (((lo_ >> 9) & 1u) << 5);
  const uint32_t aRegion = (uint32_t)(wr >> 7) * 16384u;
  const uint32_t smem_base = (uint32_t)(size_t)&smem_[0];
  const uint32_t aBase = smem_base + aRegion + lane_off;  // + parity + quad*4096

  // per-n B fragment base addresses (row = wc + n*16 within B panel)
  uint32_t bA[WN];
#pragma unroll
  for (int n = 0; n < WN; ++n) {
    const uint32_t row = (uint32_t)(wc + n * 16);
    bA[n] = smem_base + 32768u + (row >> 6) * 8192u + ((row & 63u) >> 4) * 2048u + lane_off;
  }

  // stage one 64-row unit of tile `tile` into parity (tile&1)
  auto STAGE1 = [&](const bf16* mat, int unit, int tile, uint32_t isB) {
    uint32_t dst = (uint32_t)(tile & 1) * PARB + isB + (uint32_t)unit * 8192u + (uint32_t)t * 16u;
    const bf16* src = mat + (long)(unit * 64 + r0) * K + tile * 64 + c0;
    GLOAD16(src, smem_ + (dst >> 1));
  };

  f32x4 acc[8][WN] = {};

  // ---- prologue: A(0) + B(0) into parity 0
  STAGE1(Ab, 0, 0, 0u); STAGE1(Ab, 1, 0, 0u); STAGE1(Ab, 2, 0, 0u); STAGE1(Ab, 3, 0, 0u);
#pragma unroll
  for (int u = 0; u < WN; ++u) STAGE1(Bb, u, 0, 32768u);
  SB();  // pin gloads above the count-wait
  WAIT_VM0();
  __builtin_amdgcn_s_barrier();

  // MFMA for output quad Q (acc rows Q*2, Q*2+1) using aF slot S
#define MFMAQ(Q, S)                                                                  \
  _Pragma("unroll") for (int mi = 0; mi < 2; ++mi)                                   \
  _Pragma("unroll") for (int n = 0; n < WN; ++n)                                     \
  _Pragma("unroll") for (int kk = 0; kk < 2; ++kk)                                   \
    acc[(Q) * 2 + mi][n] = __builtin_amdgcn_mfma_f32_16x16x32_bf16(                  \
        __builtin_bit_cast(bf16x8, aF[S][mi][kk]), __builtin_bit_cast(bf16x8, bF[n][kk]), \
        acc[(Q) * 2 + mi][n], 0, 0, 0);

  for (int T = 0; T < NT; ++T) {
    const uint32_t pb = (uint32_t)(T & 1) * PARB;
    const uint32_t aA = aBase + pb;
    f32x4 bF[WN][2];
    f32x4 aF[2][2][2];  // [slot][mi][kk]

    // ---- front-load ALL staging of tile T+1 (other parity; WAR-safe) ----
    if (T + 1 < NT) {
#pragma unroll
      for (int u = 0; u < WN; ++u) STAGE1(Bb, u, T + 1, 32768u);
      STAGE1(Ab, 0, T + 1, 0u); STAGE1(Ab, 1, T + 1, 0u);
      STAGE1(Ab, 2, T + 1, 0u); STAGE1(Ab, 3, T + 1, 0u);
    }

    // ---- phase A: issue bF(2WN) + aF q0(4) + q1(4) ----
#pragma unroll
    for (int n = 0; n < WN; ++n) {
      DSR(bF[n][0], bA[n] + pb, "0");
      DSR(bF[n][1], bA[n] + pb, "1024");
    }
    DSR(aF[0][0][0], aA, "0");    DSR(aF[0][0][1], aA, "1024");
    DSR(aF[0][1][0], aA, "2048"); DSR(aF[0][1][1], aA, "3072");
    DSR(aF[1][0][0], aA, "4096"); DSR(aF[1][0][1], aA, "5120");
    DSR(aF[1][1][0], aA, "6144"); DSR(aF[1][1][1], aA, "7168");
    WAIT_LGKM4();   // bF + q0 landed; q1 (4 reads) in flight
    SB();           // rule #18: keep MFMA below the wait
    __builtin_amdgcn_s_setprio(1);
    MFMAQ(0, 0)
    __builtin_amdgcn_s_setprio(0);
    WAIT_LGKM0();   // q1 landed
    SB();
    __builtin_amdgcn_s_setprio(1);
    MFMAQ(1, 1)
    __builtin_amdgcn_s_setprio(0);

    // ---- phase B: issue aF q2(4) + q3(4), reuse slots ----
    DSR(aF[0][0][0], aA, "8192");  DSR(aF[0][0][1], aA, "9216");
    DSR(aF[0][1][0], aA, "10240"); DSR(aF[0][1][1], aA, "11264");
    DSR(aF[1][0][0], aA, "12288"); DSR(aF[1][0][1], aA, "13312");
    DSR(aF[1][1][0], aA, "14336"); DSR(aF[1][1][1], aA, "15360");
    WAIT_LGKM4();   // q2 landed; q3 in flight
    SB();
    __builtin_amdgcn_s_setprio(1);
    MFMAQ(2, 0)
    __builtin_amdgcn_s_setprio(0);
    WAIT_LGKM0();   // q3 landed
    SB();
    __builtin_amdgcn_s_setprio(1);
    MFMAQ(3, 1)
    __builtin_amdgcn_s_setprio(0);

    // ---- boundary: T+1 stages landed & visible to all waves ----
    SB();  // pin gloads above the count-wait
    WAIT_VM0();
    __builtin_amdgcn_s_barrier();
  }
#undef MFMAQ

  // ---- epilogue: C/D layout col = lane&15, row = (lane>>4)*4 + i
  const int orow0 = blockIdx.y * 256 + wr + (l >> 4) * 4;
  const int ocol0 = blockIdx.x * BN + wc + (l & 15);
#pragma unroll
  for (int m = 0; m < 8; ++m)
#pragma unroll
    for (int n = 0; n < WN; ++n)
#pragma unroll
      for (int i = 0; i < 4; ++i) {
        const long r = orow0 + m * 16 + i;
        const long c = ocol0 + n * 16;
        const float v = acc[m][n][i] * alpha;
        if constexpr (EPI == 0) {
          ((bf16*)Cp)[z * sC + r * ldc + c] = (bf16)v;
        } else if constexpr (EPI == 2) {
          ((float*)Cp)[r * ldc + c] = v;
        } else if constexpr (EPI == 4) {
          // V-proj -> Vt[b][e][s]: r = b*2048+s, c = e
          ((bf16*)Cp)[(r >> 11) * 2097152 + c * 2048 + (r & 2047)] = (bf16)v;
        } else {
          // QK-proj route: c<1024 -> Q, else K  (rows r = b*2048+s)
          bf16* Qb = (bf16*)Cp;
          bf16* Kb = Qb + 8388608;  // 8192*1024
          if (c < 1024) Qb[r * 1024 + c] = (bf16)v;
          else Kb[r * 1024 + (c - 1024)] = (bf16)v;
        }
      }
}

// ---------------- row softmax, in place, rows of 2048 bf16 ----------------
__global__ __launch_bounds__(256) void softmax_rows(bf16* __restrict__ P) {
  const long row = blockIdx.x;
  bf16* p = P + row * 2048;
  const int t = threadIdx.x;
  const int lane = t & 63;
  const int wave = t >> 6;

  u16x8 raw = *reinterpret_cast<const u16x8*>(p + t * 8);
  float v[8];
#pragma unroll
  for (int j = 0; j < 8; ++j) {
    uint32_t bits = ((uint32_t)raw[j]) << 16;
    v[j] = __builtin_bit_cast(float, bits);
  }
  float m = v[0];
#pragma unroll
  for (int j = 1; j < 8; ++j) m = fmaxf(m, v[j]);
#pragma unroll
  for (int off = 32; off > 0; off >>= 1) m = fmaxf(m, __shfl_xor(m, off, 64));
  __shared__ float redm[4];
  __shared__ float reds[4];
  if (lane == 0) redm[wave] = m;
  __syncthreads();
  m = fmaxf(fmaxf(redm[0], redm[1]), fmaxf(redm[2], redm[3]));

  float s = 0.f;
#pragma unroll
  for (int j = 0; j < 8; ++j) {
    v[j] = __expf(v[j] - m);
    s += v[j];
  }
#pragma unroll
  for (int off = 32; off > 0; off >>= 1) s += __shfl_xor(s, off, 64);
  if (lane == 0) reds[wave] = s;
  __syncthreads();
  s = reds[0] + reds[1] + reds[2] + reds[3];
  const float inv = 1.f / s;

  u16x8 o;
#pragma unroll
  for (int j = 0; j < 8; ++j) o[j] = __builtin_bit_cast(unsigned short, (bf16)(v[j] * inv));
  *reinterpret_cast<u16x8*>(p + t * 8) = o;
}

// ---------------- launch ----------------
extern "C" void kernel_launch(void* const* d_in, const int* in_sizes, int n_in,
                              void* d_out, int out_size, void* d_ws, size_t ws_size,
                              hipStream_t stream) {
  const float* q = (const float*)d_in[0];
  const float* wq = (const float*)d_in[1];
  const float* wk = (const float*)d_in[2];
  const float* wv = (const float*)d_in[3];
  const float* wo = (const float*)d_in[4];
  float* out = (float*)d_out;

  constexpr int B = 4, S = 2048, D = 1024;
  constexpr long SD = (long)S * D;  // 2,097,152
  constexpr long SS = (long)S * S;  // 4,194,304
  constexpr long DD = (long)D * D;  // 1,048,576

  bf16* wsb = (bf16*)d_ws;
  bf16* qb = wsb;             // B*SD
  bf16* W3 = qb + B * SD;     // 3*DD  (wq;wk;wv stacked rows)
  bf16* wob = W3 + 3 * DD;    // DD
  bf16* Qb = wob + DD;        // B*SD
  bf16* Kb = Qb + B * SD;     // B*SD
  bf16* Vt = Kb + B * SD;     // B*SD, layout [B][D][S]
  bf16* P = Vt + B * SD;      // B*SS
  bf16* X = P + B * SS;       // B*SD, layout [B][D][S] == bugged buffer

  cvt_all<<<3072, 256, 0, stream>>>(q, wq, wk, wv, wo, qb, W3, wob);

  // QK-proj: [8192x1024] @ [2048x1024]^T -> Qb,Kb. WN=4, 256 blocks = 1/CU.
  g256<5, 4><<<dim3(8, 32, 1), 512, 0, stream>>>(qb, W3, Qb, D, 1.f, 0, 0, 0, 0);
  // V-proj: [8192x1024] @ [1024x1024]^T -> Vt (transposed). WN=2, 256 blocks.
  g256<4, 2><<<dim3(8, 32, 1), 512, 0, stream>>>(qb, W3 + 2 * DD, Vt, D, 1.f, 0, 0, 0, 0);
  // scores: P[b][i][j] = Q.K/8  (per batch 2048x2048, K=1024), 256 blocks = 1/CU
  g256<0, 4><<<dim3(8, 8, B), 512, 0, stream>>>(Qb, Kb, P, D, 0.125f, SD, SD, SS, S);
  softmax_rows<<<B * S, 256, 0, stream>>>(P);
  // PV as Xt = Vt @ P^T (M=1024, N=2048, K=2048): 256x128 tile, 256 blocks = 1/CU
  g256<0, 2><<<dim3(16, 4, B), 512, 0, stream>>>(Vt, P, X, S, 1.f, SD, SS, SD, S);
  // out = Xflat[8192x1024] @ wo^T -> f32: 256x128, 256 blocks = 1/CU
  g256<2, 2><<<dim3(8, 32, 1), 512, 0, stream>>>(X, wob, out, D, 1.f, 0, 0, 0, D);
}

// Round 16
// 202.462 us; speedup vs baseline: 1.0148x; 1.0142x over previous
//
#include <hip/hip_runtime.h>
#include <hip/hip_bf16.h>
#include <stdint.h>

typedef __bf16 bf16;
typedef __attribute__((ext_vector_type(8))) __bf16 bf16x8;
typedef __attribute__((ext_vector_type(4))) float f32x4;
typedef __attribute__((ext_vector_type(8))) unsigned short u16x8;

#define LDS_U32 __attribute__((address_space(3))) uint32_t
#define GLB_U32 const __attribute__((address_space(1))) uint32_t
#define GLOAD16(g, l) __builtin_amdgcn_global_load_lds((GLB_U32*)(g), (LDS_U32*)(l), 16, 0, 0)

#define DSR(dst, addr, OFFLIT) \
  asm volatile("ds_read_b128 %0, %1 offset:" OFFLIT : "=v"(dst) : "v"(addr))

#define WAIT_LGKM0() asm volatile("s_waitcnt lgkmcnt(0)")
#define WAIT_LGKM4() asm volatile("s_waitcnt lgkmcnt(4)")
#define WAIT_VMN(n)  asm volatile("s_waitcnt vmcnt(" #n ")")
#define SB()         __builtin_amdgcn_sched_barrier(0)

// ---------------- fused f32 -> bf16 convert (all 5 inputs, one launch) ----------------
__global__ __launch_bounds__(256) void cvt_all(const float* __restrict__ q,
                                               const float* __restrict__ wq,
                                               const float* __restrict__ wk,
                                               const float* __restrict__ wv,
                                               const float* __restrict__ wo,
                                               bf16* __restrict__ qb,
                                               bf16* __restrict__ W3,
                                               bf16* __restrict__ wob) {
  const int b = blockIdx.x;
  const float* src;
  bf16* dst;
  int within;
  if (b < 2048) { src = q; dst = qb; within = b; }
  else {
    const int seg = (b - 2048) >> 8;      // 0..3
    within = (b - 2048) & 255;
    if (seg == 0)      { src = wq; dst = W3; }
    else if (seg == 1) { src = wk; dst = W3 + 1048576; }
    else if (seg == 2) { src = wv; dst = W3 + 2097152; }
    else               { src = wo; dst = wob; }
  }
  const int off = within * 1024;
#pragma unroll
  for (int it = 0; it < 4; ++it) {
    const int j = off + it * 256 + threadIdx.x;
    float4 v = reinterpret_cast<const float4*>(src)[j];
    ushort4 o;
    o.x = __builtin_bit_cast(unsigned short, (bf16)v.x);
    o.y = __builtin_bit_cast(unsigned short, (bf16)v.y);
    o.z = __builtin_bit_cast(unsigned short, (bf16)v.z);
    o.w = __builtin_bit_cast(unsigned short, (bf16)v.w);
    reinterpret_cast<ushort4*>(dst)[j] = o;
  }
}

// ============ 256 x (WN*64) double-buffered GEMM, C = alpha * A @ B^T ============
// r16: counted-vmcnt pipeline (T4), RACE-FIXED. r15's bug: phase A (quads
// 0,1 at aRegion+0/+4096) reads A units {0,2} (one per 128-row wave-half:
// aRegion=(wr>>7)*16384, unit = 8KB), NOT {0,1}. r15 left A2 in flight at
// the boundary -> waves 4-7 read it before landing (absmax 0.55).
// Corrected stagger (per-wave FIFO verified):
//   top of T:  issue B(T+1) x WN, A0(T+1), A2(T+1)   [phase-A readers' units]
//   mid of T:  issue A1(T+1), A3(T+1)                [phase-B readers' units]
//   mid wait:  vmcnt(WN+4) + s_barrier -> retires A1,A3(T) (issued mid T-1)
//   boundary:  vmcnt(2)    + s_barrier -> retires B,A0,A2(T+1);
//              A1,A3(T+1) stay IN FLIGHT across the barrier (T4 signature:
//              the memory pipe is never drained mid-loop).
// Last-tile edges use vmcnt(0). Intra-phase counted lgkm kept from r13.
// LDS per parity: A 32KB (4 units x 8KB, 64 rows x 64k) + B WN*8KB;
// PARB = 32768 + WN*8192; 2 parities. st_16x32 swizzle both sides.
// EPI: 0 = bf16 C[z*sC+r*ldc+c]; 2 = f32 C[r*ldc+c];
//      4 = Vt scatter: Vt[(r>>11)*2097152 + c*2048 + (r&2047)];
//      5 = QK route: c<1024 -> Qb[r*1024+c], else Kb[r*1024+c-1024].
template <int EPI, int WN>
__global__ __launch_bounds__(512, 2) void g256(const bf16* __restrict__ A,
                                               const bf16* __restrict__ Bm,
                                               void* __restrict__ Cp,
                                               int K, float alpha,
                                               long sA, long sB, long sC, int ldc) {
  constexpr int BN = WN * 64;
  constexpr uint32_t PARB = 32768u + WN * 8192u;  // parity stride in bytes
  __shared__ bf16 smem_[PARB];                    // 2 parities x PARB bytes
  const long z = blockIdx.z;
  const int t = threadIdx.x;
  const int l = t & 63;
  const int w = t >> 6;
  const int wr = (w >> 2) * 128;        // wave row base within 256
  const int wc = (w & 3) * (WN * 16);   // wave col base within BN
  const int NT = K >> 6;

  const bf16* Ab = A + z * sA + (long)(blockIdx.y * 256) * K;
  const bf16* Bb = Bm + z * sB + (long)(blockIdx.x * BN) * K;

  // staging inverse map: thread t covers swizzled bytes [t*16, t*16+16) of one
  // 8KB 64-row unit; (r0,c0) = source row/col within the unit.
  uint32_t loc = (uint32_t)t * 16u;
  uint32_t g0 = loc ^ (((loc >> 9) & 1u) << 5);
  const int r0 = (int)(((g0 >> 10) >> 1) * 16 + ((g0 >> 6) & 15));  // 0..63
  const int c0 = (int)(((g0 >> 10) & 1) * 32 + ((g0 & 63) >> 1));   // 0..63

  // per-lane swizzled fragment read offset
  uint32_t lo_ = (uint32_t)((l & 15) * 64 + (l >> 4) * 16);
  const uint32_t lane_off = lo_ ^ (((lo_ >> 9) & 1u) << 5);
  const uint32_t aRegion = (uint32_t)(wr >> 7) * 16384u;
  const uint32_t smem_base = (uint32_t)(size_t)&smem_[0];
  const uint32_t aBase = smem_base + aRegion + lane_off;  // + parity + quad*4096

  // per-n B fragment base addresses (row = wc + n*16 within B panel)
  uint32_t bA[WN];
#pragma unroll
  for (int n = 0; n < WN; ++n) {
    const uint32_t row = (uint32_t)(wc + n * 16);
    bA[n] = smem_base + 32768u + (row >> 6) * 8192u + ((row & 63u) >> 4) * 2048u + lane_off;
  }

  // stage one 64-row unit of tile `tile` into parity (tile&1)
  auto STAGE1 = [&](const bf16* mat, int unit, int tile, uint32_t isB) {
    uint32_t dst = (uint32_t)(tile & 1) * PARB + isB + (uint32_t)unit * 8192u + (uint32_t)t * 16u;
    const bf16* src = mat + (long)(unit * 64 + r0) * K + tile * 64 + c0;
    GLOAD16(src, smem_ + (dst >> 1));
  };

  f32x4 acc[8][WN] = {};

  // ---- prologue: A(0) + B(0) into parity 0 (one-time full drain)
  STAGE1(Ab, 0, 0, 0u); STAGE1(Ab, 1, 0, 0u); STAGE1(Ab, 2, 0, 0u); STAGE1(Ab, 3, 0, 0u);
#pragma unroll
  for (int u = 0; u < WN; ++u) STAGE1(Bb, u, 0, 32768u);
  SB();
  WAIT_VMN(0);
  __builtin_amdgcn_s_barrier();

  // MFMA for output quad Q (acc rows Q*2, Q*2+1) using aF slot S
#define MFMAQ(Q, S)                                                                  \
  _Pragma("unroll") for (int mi = 0; mi < 2; ++mi)                                   \
  _Pragma("unroll") for (int n = 0; n < WN; ++n)                                     \
  _Pragma("unroll") for (int kk = 0; kk < 2; ++kk)                                   \
    acc[(Q) * 2 + mi][n] = __builtin_amdgcn_mfma_f32_16x16x32_bf16(                  \
        __builtin_bit_cast(bf16x8, aF[S][mi][kk]), __builtin_bit_cast(bf16x8, bF[n][kk]), \
        acc[(Q) * 2 + mi][n], 0, 0, 0);

  for (int T = 0; T < NT; ++T) {
    const uint32_t pb = (uint32_t)(T & 1) * PARB;
    const uint32_t aA = aBase + pb;
    f32x4 bF[WN][2];
    f32x4 aF[2][2][2];  // [slot][mi][kk]

    // ---- top: issue B(T+1) + A units {0,2} (phase-A readers: quads 0,1
    // live in the first 8KB of EACH 128-row half = units 0 and 2) ----
    if (T + 1 < NT) {
#pragma unroll
      for (int u = 0; u < WN; ++u) STAGE1(Bb, u, T + 1, 32768u);
      STAGE1(Ab, 0, T + 1, 0u); STAGE1(Ab, 2, T + 1, 0u);
    }

    // ---- phase A: issue bF(2WN) + aF q0(4) + q1(4); data landed last tile ----
#pragma unroll
    for (int n = 0; n < WN; ++n) {
      DSR(bF[n][0], bA[n] + pb, "0");
      DSR(bF[n][1], bA[n] + pb, "1024");
    }
    DSR(aF[0][0][0], aA, "0");    DSR(aF[0][0][1], aA, "1024");
    DSR(aF[0][1][0], aA, "2048"); DSR(aF[0][1][1], aA, "3072");
    DSR(aF[1][0][0], aA, "4096"); DSR(aF[1][0][1], aA, "5120");
    DSR(aF[1][1][0], aA, "6144"); DSR(aF[1][1][1], aA, "7168");
    WAIT_LGKM4();   // bF + q0 landed; q1 (4 reads) in flight
    SB();           // rule #18: keep MFMA below the wait
    __builtin_amdgcn_s_setprio(1);
    MFMAQ(0, 0)
    __builtin_amdgcn_s_setprio(0);
    WAIT_LGKM0();   // q1 landed
    SB();
    __builtin_amdgcn_s_setprio(1);
    MFMAQ(1, 1)
    __builtin_amdgcn_s_setprio(0);

    // ---- mid: issue A units {1,3} of T+1 (phase-B readers' units) ----
    if (T + 1 < NT) { STAGE1(Ab, 1, T + 1, 0u); STAGE1(Ab, 3, T + 1, 0u); }

    // ---- mid wait: A1,A3(T) landed (issued mid of T-1; 1-tile cover).
    // Outstanding: A1,A3(T) x2 [oldest] + B,A0,A2(T+1) x(WN+2) + A1,A3(T+1) x2.
    SB();
    if (T + 1 < NT) {
      if constexpr (WN == 2) { WAIT_VMN(6); } else { WAIT_VMN(8); }
    } else {
      WAIT_VMN(0);
    }
    __builtin_amdgcn_s_barrier();

    // ---- phase B: issue aF q2(4) + q3(4), reuse slots ----
    DSR(aF[0][0][0], aA, "8192");  DSR(aF[0][0][1], aA, "9216");
    DSR(aF[0][1][0], aA, "10240"); DSR(aF[0][1][1], aA, "11264");
    DSR(aF[1][0][0], aA, "12288"); DSR(aF[1][0][1], aA, "13312");
    DSR(aF[1][1][0], aA, "14336"); DSR(aF[1][1][1], aA, "15360");
    WAIT_LGKM4();   // q2 landed; q3 in flight
    SB();
    __builtin_amdgcn_s_setprio(1);
    MFMAQ(2, 0)
    __builtin_amdgcn_s_setprio(0);
    WAIT_LGKM0();   // q3 landed
    SB();
    __builtin_amdgcn_s_setprio(1);
    MFMAQ(3, 1)
    __builtin_amdgcn_s_setprio(0);

    // ---- boundary: B,A0,A2(T+1) landed; A1,A3(T+1) STAY IN FLIGHT ----
    SB();
    if (T + 1 < NT) { WAIT_VMN(2); } else { WAIT_VMN(0); }
    __builtin_amdgcn_s_barrier();
  }
#undef MFMAQ

  // ---- epilogue: C/D layout col = lane&15, row = (lane>>4)*4 + i
  const int orow0 = blockIdx.y * 256 + wr + (l >> 4) * 4;
  const int ocol0 = blockIdx.x * BN + wc + (l & 15);
#pragma unroll
  for (int m = 0; m < 8; ++m)
#pragma unroll
    for (int n = 0; n < WN; ++n)
#pragma unroll
      for (int i = 0; i < 4; ++i) {
        const long r = orow0 + m * 16 + i;
        const long c = ocol0 + n * 16;
        const float v = acc[m][n][i] * alpha;
        if constexpr (EPI == 0) {
          ((bf16*)Cp)[z * sC + r * ldc + c] = (bf16)v;
        } else if constexpr (EPI == 2) {
          ((float*)Cp)[r * ldc + c] = v;
        } else if constexpr (EPI == 4) {
          // V-proj -> Vt[b][e][s]: r = b*2048+s, c = e
          ((bf16*)Cp)[(r >> 11) * 2097152 + c * 2048 + (r & 2047)] = (bf16)v;
        } else {
          // QK-proj route: c<1024 -> Q, else K  (rows r = b*2048+s)
          bf16* Qb = (bf16*)Cp;
          bf16* Kb = Qb + 8388608;  // 8192*1024
          if (c < 1024) Qb[r * 1024 + c] = (bf16)v;
          else Kb[r * 1024 + (c - 1024)] = (bf16)v;
        }
      }
}

// ---------------- row softmax, in place, rows of 2048 bf16 ----------------
__global__ __launch_bounds__(256) void softmax_rows(bf16* __restrict__ P) {
  const long row = blockIdx.x;
  bf16* p = P + row * 2048;
  const int t = threadIdx.x;
  const int lane = t & 63;
  const int wave = t >> 6;

  u16x8 raw = *reinterpret_cast<const u16x8*>(p + t * 8);
  float v[8];
#pragma unroll
  for (int j = 0; j < 8; ++j) {
    uint32_t bits = ((uint32_t)raw[j]) << 16;
    v[j] = __builtin_bit_cast(float, bits);
  }
  float m = v[0];
#pragma unroll
  for (int j = 1; j < 8; ++j) m = fmaxf(m, v[j]);
#pragma unroll
  for (int off = 32; off > 0; off >>= 1) m = fmaxf(m, __shfl_xor(m, off, 64));
  __shared__ float redm[4];
  __shared__ float reds[4];
  if (lane == 0) redm[wave] = m;
  __syncthreads();
  m = fmaxf(fmaxf(redm[0], redm[1]), fmaxf(redm[2], redm[3]));

  float s = 0.f;
#pragma unroll
  for (int j = 0; j < 8; ++j) {
    v[j] = __expf(v[j] - m);
    s += v[j];
  }
#pragma unroll
  for (int off = 32; off > 0; off >>= 1) s += __shfl_xor(s, off, 64);
  if (lane == 0) reds[wave] = s;
  __syncthreads();
  s = reds[0] + reds[1] + reds[2] + reds[3];
  const float inv = 1.f / s;

  u16x8 o;
#pragma unroll
  for (int j = 0; j < 8; ++j) o[j] = __builtin_bit_cast(unsigned short, (bf16)(v[j] * inv));
  *reinterpret_cast<u16x8*>(p + t * 8) = o;
}

// ---------------- launch ----------------
extern "C" void kernel_launch(void* const* d_in, const int* in_sizes, int n_in,
                              void* d_out, int out_size, void* d_ws, size_t ws_size,
                              hipStream_t stream) {
  const float* q = (const float*)d_in[0];
  const float* wq = (const float*)d_in[1];
  const float* wk = (const float*)d_in[2];
  const float* wv = (const float*)d_in[3];
  const float* wo = (const float*)d_in[4];
  float* out = (float*)d_out;

  constexpr int B = 4, S = 2048, D = 1024;
  constexpr long SD = (long)S * D;  // 2,097,152
  constexpr long SS = (long)S * S;  // 4,194,304
  constexpr long DD = (long)D * D;  // 1,048,576

  bf16* wsb = (bf16*)d_ws;
  bf16* qb = wsb;             // B*SD
  bf16* W3 = qb + B * SD;     // 3*DD  (wq;wk;wv stacked rows)
  bf16* wob = W3 + 3 * DD;    // DD
  bf16* Qb = wob + DD;        // B*SD
  bf16* Kb = Qb + B * SD;     // B*SD
  bf16* Vt = Kb + B * SD;     // B*SD, layout [B][D][S]
  bf16* P = Vt + B * SD;      // B*SS
  bf16* X = P + B * SS;       // B*SD, layout [B][D][S] == bugged buffer

  cvt_all<<<3072, 256, 0, stream>>>(q, wq, wk, wv, wo, qb, W3, wob);

  // QK-proj: [8192x1024] @ [2048x1024]^T -> Qb,Kb. WN=4, 256 blocks = 1/CU.
  g256<5, 4><<<dim3(8, 32, 1), 512, 0, stream>>>(qb, W3, Qb, D, 1.f, 0, 0, 0, 0);
  // V-proj: [8192x1024] @ [1024x1024]^T -> Vt (transposed). WN=2, 256 blocks.
  g256<4, 2><<<dim3(8, 32, 1), 512, 0, stream>>>(qb, W3 + 2 * DD, Vt, D, 1.f, 0, 0, 0, 0);
  // scores: P[b][i][j] = Q.K/8  (per batch 2048x2048, K=1024), 256 blocks = 1/CU
  g256<0, 4><<<dim3(8, 8, B), 512, 0, stream>>>(Qb, Kb, P, D, 0.125f, SD, SD, SS, S);
  softmax_rows<<<B * S, 256, 0, stream>>>(P);
  // PV as Xt = Vt @ P^T (M=1024, N=2048, K=2048): 256x128 tile, 256 blocks = 1/CU
  g256<0, 2><<<dim3(16, 4, B), 512, 0, stream>>>(Vt, P, X, S, 1.f, SD, SS, SD, S);
  // out = Xflat[8192x1024] @ wo^T -> f32: 256x128, 256 blocks = 1/CU
  g256<2, 2><<<dim3(8, 32, 1), 512, 0, stream>>>(X, wob, out, D, 1.f, 0, 0, 0, D);
}

// Round 17
// 196.705 us; speedup vs baseline: 1.0445x; 1.0293x over previous
//
#include <hip/hip_runtime.h>
#include <hip/hip_bf16.h>
#include <stdint.h>

typedef __bf16 bf16;
typedef __attribute__((ext_vector_type(8))) __bf16 bf16x8;
typedef __attribute__((ext_vector_type(4))) float f32x4;
typedef __attribute__((ext_vector_type(8))) unsigned short u16x8;

#define LDS_U32 __attribute__((address_space(3))) uint32_t
#define GLB_U32 const __attribute__((address_space(1))) uint32_t
#define GLOAD16(g, l) __builtin_amdgcn_global_load_lds((GLB_U32*)(g), (LDS_U32*)(l), 16, 0, 0)

#define DSR(dst, addr, OFFLIT) \
  asm volatile("ds_read_b128 %0, %1 offset:" OFFLIT : "=v"(dst) : "v"(addr))

#define WAIT_LGKM0() asm volatile("s_waitcnt lgkmcnt(0)")
#define WAIT_LGKM4() asm volatile("s_waitcnt lgkmcnt(4)")
#define WAIT_VMN(n)  asm volatile("s_waitcnt vmcnt(" #n ")")
#define SB()         __builtin_amdgcn_sched_barrier(0)

// ---------------- fused f32 -> bf16 convert (all 5 inputs, one launch) ----------------
__global__ __launch_bounds__(256) void cvt_all(const float* __restrict__ q,
                                               const float* __restrict__ wq,
                                               const float* __restrict__ wk,
                                               const float* __restrict__ wv,
                                               const float* __restrict__ wo,
                                               bf16* __restrict__ qb,
                                               bf16* __restrict__ W3,
                                               bf16* __restrict__ wob) {
  const int b = blockIdx.x;
  const float* src;
  bf16* dst;
  int within;
  if (b < 2048) { src = q; dst = qb; within = b; }
  else {
    const int seg = (b - 2048) >> 8;      // 0..3
    within = (b - 2048) & 255;
    if (seg == 0)      { src = wq; dst = W3; }
    else if (seg == 1) { src = wk; dst = W3 + 1048576; }
    else if (seg == 2) { src = wv; dst = W3 + 2097152; }
    else               { src = wo; dst = wob; }
  }
  const int off = within * 1024;
#pragma unroll
  for (int it = 0; it < 4; ++it) {
    const int j = off + it * 256 + threadIdx.x;
    float4 v = reinterpret_cast<const float4*>(src)[j];
    ushort4 o;
    o.x = __builtin_bit_cast(unsigned short, (bf16)v.x);
    o.y = __builtin_bit_cast(unsigned short, (bf16)v.y);
    o.z = __builtin_bit_cast(unsigned short, (bf16)v.z);
    o.w = __builtin_bit_cast(unsigned short, (bf16)v.w);
    reinterpret_cast<ushort4*>(dst)[j] = o;
  }
}

// ============ 256 x (WN*64) double-buffered GEMM, C = alpha * A @ B^T ============
// r17: + XCD-AWARE BIJECTIVE BLOCK SWIZZLE (T1, m204 formula). Evidence: r16's
// per-tile time (~6.2 kcyc) is invariant to MFMA count (V-proj 17 GF == scores
// 34 GF == 42 us) and to LDS-read count -> the binder is the 64KB/tile staging
// fetch: 64KB / 6.2kcyc x 256 CU ~= 6.3 TB/s = the L3-path ceiling. Default
// round-robin block->XCD placement gives ~zero per-XCD L2 reuse (neighboring
// tiles that share A/B panels sit on different XCDs). Remap so each XCD owns
// a CONTIGUOUS chunk of the per-z grid: per-K-step working set ~384 KB << 4MB
// L2; each K-slice is fetched from L3 once per XCD, then L2-served at 34.5TB/s.
// HW: xcd = dispatch_flat % 8; all per-z grids here are %8==0, and per-z bases
// are %8==0, so within-z parity == global parity (bijective, m204 with r=0).
// Pipeline (r16, race-fixed counted-vmcnt): top of T issues B(T+1)+A{0,2},
// mid issues A{1,3}; mid wait vmcnt(WN+4) retires A{1,3}(T); boundary vmcnt(2)
// retires B,A0,A2(T+1), leaves A1,A3(T+1) in flight. Counted lgkm intra-phase.
// EPI: 0 = bf16 C[z*sC+r*ldc+c]; 2 = f32 C[r*ldc+c];
//      4 = Vt scatter: Vt[(r>>11)*2097152 + c*2048 + (r&2047)];
//      5 = QK route: c<1024 -> Qb[r*1024+c], else Kb[r*1024+c-1024].
template <int EPI, int WN>
__global__ __launch_bounds__(512, 2) void g256(const bf16* __restrict__ A,
                                               const bf16* __restrict__ Bm,
                                               void* __restrict__ Cp,
                                               int K, float alpha,
                                               long sA, long sB, long sC, int ldc) {
  constexpr int BN = WN * 64;
  constexpr uint32_t PARB = 32768u + WN * 8192u;  // parity stride in bytes
  __shared__ bf16 smem_[PARB];                    // 2 parities x PARB bytes
  const long z = blockIdx.z;
  const int t = threadIdx.x;
  const int l = t & 63;
  const int w = t >> 6;
  const int wr = (w >> 2) * 128;        // wave row base within 256
  const int wc = (w & 3) * (WN * 16);   // wave col base within BN
  const int NT = K >> 6;

  // ---- XCD-aware bijective swizzle of the within-z flat block index ----
  int bx, by;
  {
    const int gx = (int)gridDim.x;
    const int nxy = gx * (int)gridDim.y;
    int f = (int)blockIdx.y * gx + (int)blockIdx.x;  // hw dispatch order within z
    if ((nxy & 7) == 0) {
      const int qq = nxy >> 3;
      const int wg = (f & 7) * qq + (f >> 3);  // XCD (f&7) owns contiguous chunk
      bx = wg % gx;
      by = wg / gx;
    } else {
      bx = (int)blockIdx.x;
      by = (int)blockIdx.y;
    }
  }

  const bf16* Ab = A + z * sA + (long)(by * 256) * K;
  const bf16* Bb = Bm + z * sB + (long)(bx * BN) * K;

  // staging inverse map: thread t covers swizzled bytes [t*16, t*16+16) of one
  // 8KB 64-row unit; (r0,c0) = source row/col within the unit.
  uint32_t loc = (uint32_t)t * 16u;
  uint32_t g0 = loc ^ (((loc >> 9) & 1u) << 5);
  const int r0 = (int)(((g0 >> 10) >> 1) * 16 + ((g0 >> 6) & 15));  // 0..63
  const int c0 = (int)(((g0 >> 10) & 1) * 32 + ((g0 & 63) >> 1));   // 0..63

  // per-lane swizzled fragment read offset
  uint32_t lo_ = (uint32_t)((l & 15) * 64 + (l >> 4) * 16);
  const uint32_t lane_off = lo_ ^ (((lo_ >> 9) & 1u) << 5);
  const uint32_t aRegion = (uint32_t)(wr >> 7) * 16384u;
  const uint32_t smem_base = (uint32_t)(size_t)&smem_[0];
  const uint32_t aBase = smem_base + aRegion + lane_off;  // + parity + quad*4096

  // per-n B fragment base addresses (row = wc + n*16 within B panel)
  uint32_t bA[WN];
#pragma unroll
  for (int n = 0; n < WN; ++n) {
    const uint32_t row = (uint32_t)(wc + n * 16);
    bA[n] = smem_base + 32768u + (row >> 6) * 8192u + ((row & 63u) >> 4) * 2048u + lane_off;
  }

  // stage one 64-row unit of tile `tile` into parity (tile&1)
  auto STAGE1 = [&](const bf16* mat, int unit, int tile, uint32_t isB) {
    uint32_t dst = (uint32_t)(tile & 1) * PARB + isB + (uint32_t)unit * 8192u + (uint32_t)t * 16u;
    const bf16* src = mat + (long)(unit * 64 + r0) * K + tile * 64 + c0;
    GLOAD16(src, smem_ + (dst >> 1));
  };

  f32x4 acc[8][WN] = {};

  // ---- prologue: A(0) + B(0) into parity 0 (one-time full drain)
  STAGE1(Ab, 0, 0, 0u); STAGE1(Ab, 1, 0, 0u); STAGE1(Ab, 2, 0, 0u); STAGE1(Ab, 3, 0, 0u);
#pragma unroll
  for (int u = 0; u < WN; ++u) STAGE1(Bb, u, 0, 32768u);
  SB();
  WAIT_VMN(0);
  __builtin_amdgcn_s_barrier();

  // MFMA for output quad Q (acc rows Q*2, Q*2+1) using aF slot S
#define MFMAQ(Q, S)                                                                  \
  _Pragma("unroll") for (int mi = 0; mi < 2; ++mi)                                   \
  _Pragma("unroll") for (int n = 0; n < WN; ++n)                                     \
  _Pragma("unroll") for (int kk = 0; kk < 2; ++kk)                                   \
    acc[(Q) * 2 + mi][n] = __builtin_amdgcn_mfma_f32_16x16x32_bf16(                  \
        __builtin_bit_cast(bf16x8, aF[S][mi][kk]), __builtin_bit_cast(bf16x8, bF[n][kk]), \
        acc[(Q) * 2 + mi][n], 0, 0, 0);

  for (int T = 0; T < NT; ++T) {
    const uint32_t pb = (uint32_t)(T & 1) * PARB;
    const uint32_t aA = aBase + pb;
    f32x4 bF[WN][2];
    f32x4 aF[2][2][2];  // [slot][mi][kk]

    // ---- top: issue B(T+1) + A units {0,2} (phase-A readers' units) ----
    if (T + 1 < NT) {
#pragma unroll
      for (int u = 0; u < WN; ++u) STAGE1(Bb, u, T + 1, 32768u);
      STAGE1(Ab, 0, T + 1, 0u); STAGE1(Ab, 2, T + 1, 0u);
    }

    // ---- phase A: issue bF(2WN) + aF q0(4) + q1(4); data landed last tile ----
#pragma unroll
    for (int n = 0; n < WN; ++n) {
      DSR(bF[n][0], bA[n] + pb, "0");
      DSR(bF[n][1], bA[n] + pb, "1024");
    }
    DSR(aF[0][0][0], aA, "0");    DSR(aF[0][0][1], aA, "1024");
    DSR(aF[0][1][0], aA, "2048"); DSR(aF[0][1][1], aA, "3072");
    DSR(aF[1][0][0], aA, "4096"); DSR(aF[1][0][1], aA, "5120");
    DSR(aF[1][1][0], aA, "6144"); DSR(aF[1][1][1], aA, "7168");
    WAIT_LGKM4();   // bF + q0 landed; q1 (4 reads) in flight
    SB();           // rule #18: keep MFMA below the wait
    __builtin_amdgcn_s_setprio(1);
    MFMAQ(0, 0)
    __builtin_amdgcn_s_setprio(0);
    WAIT_LGKM0();   // q1 landed
    SB();
    __builtin_amdgcn_s_setprio(1);
    MFMAQ(1, 1)
    __builtin_amdgcn_s_setprio(0);

    // ---- mid: issue A units {1,3} of T+1 (phase-B readers' units) ----
    if (T + 1 < NT) { STAGE1(Ab, 1, T + 1, 0u); STAGE1(Ab, 3, T + 1, 0u); }

    // ---- mid wait: A1,A3(T) landed (issued mid of T-1; 1-tile cover).
    SB();
    if (T + 1 < NT) {
      if constexpr (WN == 2) { WAIT_VMN(6); } else { WAIT_VMN(8); }
    } else {
      WAIT_VMN(0);
    }
    __builtin_amdgcn_s_barrier();

    // ---- phase B: issue aF q2(4) + q3(4), reuse slots ----
    DSR(aF[0][0][0], aA, "8192");  DSR(aF[0][0][1], aA, "9216");
    DSR(aF[0][1][0], aA, "10240"); DSR(aF[0][1][1], aA, "11264");
    DSR(aF[1][0][0], aA, "12288"); DSR(aF[1][0][1], aA, "13312");
    DSR(aF[1][1][0], aA, "14336"); DSR(aF[1][1][1], aA, "15360");
    WAIT_LGKM4();   // q2 landed; q3 in flight
    SB();
    __builtin_amdgcn_s_setprio(1);
    MFMAQ(2, 0)
    __builtin_amdgcn_s_setprio(0);
    WAIT_LGKM0();   // q3 landed
    SB();
    __builtin_amdgcn_s_setprio(1);
    MFMAQ(3, 1)
    __builtin_amdgcn_s_setprio(0);

    // ---- boundary: B,A0,A2(T+1) landed; A1,A3(T+1) STAY IN FLIGHT ----
    SB();
    if (T + 1 < NT) { WAIT_VMN(2); } else { WAIT_VMN(0); }
    __builtin_amdgcn_s_barrier();
  }
#undef MFMAQ

  // ---- epilogue: C/D layout col = lane&15, row = (lane>>4)*4 + i
  const int orow0 = by * 256 + wr + (l >> 4) * 4;
  const int ocol0 = bx * BN + wc + (l & 15);
#pragma unroll
  for (int m = 0; m < 8; ++m)
#pragma unroll
    for (int n = 0; n < WN; ++n)
#pragma unroll
      for (int i = 0; i < 4; ++i) {
        const long r = orow0 + m * 16 + i;
        const long c = ocol0 + n * 16;
        const float v = acc[m][n][i] * alpha;
        if constexpr (EPI == 0) {
          ((bf16*)Cp)[z * sC + r * ldc + c] = (bf16)v;
        } else if constexpr (EPI == 2) {
          ((float*)Cp)[r * ldc + c] = v;
        } else if constexpr (EPI == 4) {
          // V-proj -> Vt[b][e][s]: r = b*2048+s, c = e
          ((bf16*)Cp)[(r >> 11) * 2097152 + c * 2048 + (r & 2047)] = (bf16)v;
        } else {
          // QK-proj route: c<1024 -> Q, else K  (rows r = b*2048+s)
          bf16* Qb = (bf16*)Cp;
          bf16* Kb = Qb + 8388608;  // 8192*1024
          if (c < 1024) Qb[r * 1024 + c] = (bf16)v;
          else Kb[r * 1024 + (c - 1024)] = (bf16)v;
        }
      }
}

// ---------------- row softmax, in place, rows of 2048 bf16 ----------------
__global__ __launch_bounds__(256) void softmax_rows(bf16* __restrict__ P) {
  const long row = blockIdx.x;
  bf16* p = P + row * 2048;
  const int t = threadIdx.x;
  const int lane = t & 63;
  const int wave = t >> 6;

  u16x8 raw = *reinterpret_cast<const u16x8*>(p + t * 8);
  float v[8];
#pragma unroll
  for (int j = 0; j < 8; ++j) {
    uint32_t bits = ((uint32_t)raw[j]) << 16;
    v[j] = __builtin_bit_cast(float, bits);
  }
  float m = v[0];
#pragma unroll
  for (int j = 1; j < 8; ++j) m = fmaxf(m, v[j]);
#pragma unroll
  for (int off = 32; off > 0; off >>= 1) m = fmaxf(m, __shfl_xor(m, off, 64));
  __shared__ float redm[4];
  __shared__ float reds[4];
  if (lane == 0) redm[wave] = m;
  __syncthreads();
  m = fmaxf(fmaxf(redm[0], redm[1]), fmaxf(redm[2], redm[3]));

  float s = 0.f;
#pragma unroll
  for (int j = 0; j < 8; ++j) {
    v[j] = __expf(v[j] - m);
    s += v[j];
  }
#pragma unroll
  for (int off = 32; off > 0; off >>= 1) s += __shfl_xor(s, off, 64);
  if (lane == 0) reds[wave] = s;
  __syncthreads();
  s = reds[0] + reds[1] + reds[2] + reds[3];
  const float inv = 1.f / s;

  u16x8 o;
#pragma unroll
  for (int j = 0; j < 8; ++j) o[j] = __builtin_bit_cast(unsigned short, (bf16)(v[j] * inv));
  *reinterpret_cast<u16x8*>(p + t * 8) = o;
}

// ---------------- launch ----------------
extern "C" void kernel_launch(void* const* d_in, const int* in_sizes, int n_in,
                              void* d_out, int out_size, void* d_ws, size_t ws_size,
                              hipStream_t stream) {
  const float* q = (const float*)d_in[0];
  const float* wq = (const float*)d_in[1];
  const float* wk = (const float*)d_in[2];
  const float* wv = (const float*)d_in[3];
  const float* wo = (const float*)d_in[4];
  float* out = (float*)d_out;

  constexpr int B = 4, S = 2048, D = 1024;
  constexpr long SD = (long)S * D;  // 2,097,152
  constexpr long SS = (long)S * S;  // 4,194,304
  constexpr long DD = (long)D * D;  // 1,048,576

  bf16* wsb = (bf16*)d_ws;
  bf16* qb = wsb;             // B*SD
  bf16* W3 = qb + B * SD;     // 3*DD  (wq;wk;wv stacked rows)
  bf16* wob = W3 + 3 * DD;    // DD
  bf16* Qb = wob + DD;        // B*SD
  bf16* Kb = Qb + B * SD;     // B*SD
  bf16* Vt = Kb + B * SD;     // B*SD, layout [B][D][S]
  bf16* P = Vt + B * SD;      // B*SS
  bf16* X = P + B * SS;       // B*SD, layout [B][D][S] == bugged buffer

  cvt_all<<<3072, 256, 0, stream>>>(q, wq, wk, wv, wo, qb, W3, wob);

  // QK-proj: [8192x1024] @ [2048x1024]^T -> Qb,Kb. WN=4, 256 blocks = 1/CU.
  g256<5, 4><<<dim3(8, 32, 1), 512, 0, stream>>>(qb, W3, Qb, D, 1.f, 0, 0, 0, 0);
  // V-proj: [8192x1024] @ [1024x1024]^T -> Vt (transposed). WN=2, 256 blocks.
  g256<4, 2><<<dim3(8, 32, 1), 512, 0, stream>>>(qb, W3 + 2 * DD, Vt, D, 1.f, 0, 0, 0, 0);
  // scores: P[b][i][j] = Q.K/8  (per batch 2048x2048, K=1024), 256 blocks = 1/CU
  g256<0, 4><<<dim3(8, 8, B), 512, 0, stream>>>(Qb, Kb, P, D, 0.125f, SD, SD, SS, S);
  softmax_rows<<<B * S, 256, 0, stream>>>(P);
  // PV as Xt = Vt @ P^T (M=1024, N=2048, K=2048): 256x128 tile, 256 blocks = 1/CU
  g256<0, 2><<<dim3(16, 4, B), 512, 0, stream>>>(Vt, P, X, S, 1.f, SD, SS, SD, S);
  // out = Xflat[8192x1024] @ wo^T -> f32: 256x128, 256 blocks = 1/CU
  g256<2, 2><<<dim3(8, 32, 1), 512, 0, stream>>>(X, wob, out, D, 1.f, 0, 0, 0, D);
}

// Round 18
// 184.575 us; speedup vs baseline: 1.1132x; 1.0657x over previous
//
#include <hip/hip_runtime.h>
#include <hip/hip_bf16.h>
#include <stdint.h>

typedef __bf16 bf16;
typedef __attribute__((ext_vector_type(8))) __bf16 bf16x8;
typedef __attribute__((ext_vector_type(4))) float f32x4;
typedef __attribute__((ext_vector_type(8))) unsigned short u16x8;

#define LDS_U32 __attribute__((address_space(3))) uint32_t
#define GLB_U32 const __attribute__((address_space(1))) uint32_t
#define GLOAD16(g, l) __builtin_amdgcn_global_load_lds((GLB_U32*)(g), (LDS_U32*)(l), 16, 0, 0)

#define DSR(dst, addr, OFFLIT) \
  asm volatile("ds_read_b128 %0, %1 offset:" OFFLIT : "=v"(dst) : "v"(addr))

#define WAIT_LGKM0() asm volatile("s_waitcnt lgkmcnt(0)")
#define WAIT_LGKM4() asm volatile("s_waitcnt lgkmcnt(4)")
#define WAIT_VMN(n)  asm volatile("s_waitcnt vmcnt(" #n ")")
#define SB()         __builtin_amdgcn_sched_barrier(0)

// ---------------- fused f32 -> bf16 convert (all 5 inputs, one launch) ----------------
__global__ __launch_bounds__(256) void cvt_all(const float* __restrict__ q,
                                               const float* __restrict__ wq,
                                               const float* __restrict__ wk,
                                               const float* __restrict__ wv,
                                               const float* __restrict__ wo,
                                               bf16* __restrict__ qb,
                                               bf16* __restrict__ W3,
                                               bf16* __restrict__ wob) {
  const int b = blockIdx.x;
  const float* src;
  bf16* dst;
  int within;
  if (b < 2048) { src = q; dst = qb; within = b; }
  else {
    const int seg = (b - 2048) >> 8;      // 0..3
    within = (b - 2048) & 255;
    if (seg == 0)      { src = wq; dst = W3; }
    else if (seg == 1) { src = wk; dst = W3 + 1048576; }
    else if (seg == 2) { src = wv; dst = W3 + 2097152; }
    else               { src = wo; dst = wob; }
  }
  const int off = within * 1024;
#pragma unroll
  for (int it = 0; it < 4; ++it) {
    const int j = off + it * 256 + threadIdx.x;
    float4 v = reinterpret_cast<const float4*>(src)[j];
    ushort4 o;
    o.x = __builtin_bit_cast(unsigned short, (bf16)v.x);
    o.y = __builtin_bit_cast(unsigned short, (bf16)v.y);
    o.z = __builtin_bit_cast(unsigned short, (bf16)v.z);
    o.w = __builtin_bit_cast(unsigned short, (bf16)v.w);
    reinterpret_cast<ushort4*>(dst)[j] = o;
  }
}

// ============ 256 x (WN*64) double-buffered GEMM, C = alpha * A @ B^T ============
// r18 = r17 (passed) + EPI=4 epilogue rewritten: the old per-element Vt
// scatter (2B stores at 4KB stride, 8192 transactions/wave) cost ~20us —
// V-proj (17.2 GF) took 42.4us = scores (34.4 GF). Now: transpose the block's
// 256s x 128e output through LDS (row stride 264 elems = 16B-aligned, banks
// spread) and store Vt rows coalesced (64B-contiguous 4-lane groups).
// K-loop (r16/r17, race-fixed counted-vmcnt + XCD swizzle) unchanged:
//   top of T issues B(T+1)+A{0,2}; mid issues A{1,3};
//   mid wait vmcnt(WN+4) retires A{1,3}(T); boundary vmcnt(2) retires
//   B,A0,A2(T+1), leaves A1,A3(T+1) in flight. Counted lgkm intra-phase.
// EPI: 0 = bf16 C[z*sC+r*ldc+c]; 2 = f32 C[r*ldc+c];
//      4 = Vt via LDS-transpose (WN=2 only); 5 = QK route.
template <int EPI, int WN>
__global__ __launch_bounds__(512, 2) void g256(const bf16* __restrict__ A,
                                               const bf16* __restrict__ Bm,
                                               void* __restrict__ Cp,
                                               int K, float alpha,
                                               long sA, long sB, long sC, int ldc) {
  constexpr int BN = WN * 64;
  constexpr uint32_t PARB = 32768u + WN * 8192u;  // parity stride in bytes
  __shared__ bf16 smem_[PARB];                    // 2 parities x PARB bytes
  const long z = blockIdx.z;
  const int t = threadIdx.x;
  const int l = t & 63;
  const int w = t >> 6;
  const int wr = (w >> 2) * 128;        // wave row base within 256
  const int wc = (w & 3) * (WN * 16);   // wave col base within BN
  const int NT = K >> 6;

  // ---- XCD-aware bijective swizzle of the within-z flat block index ----
  int bx, by;
  {
    const int gx = (int)gridDim.x;
    const int nxy = gx * (int)gridDim.y;
    int f = (int)blockIdx.y * gx + (int)blockIdx.x;  // hw dispatch order within z
    if ((nxy & 7) == 0) {
      const int qq = nxy >> 3;
      const int wg = (f & 7) * qq + (f >> 3);  // XCD (f&7) owns contiguous chunk
      bx = wg % gx;
      by = wg / gx;
    } else {
      bx = (int)blockIdx.x;
      by = (int)blockIdx.y;
    }
  }

  const bf16* Ab = A + z * sA + (long)(by * 256) * K;
  const bf16* Bb = Bm + z * sB + (long)(bx * BN) * K;

  // staging inverse map: thread t covers swizzled bytes [t*16, t*16+16) of one
  // 8KB 64-row unit; (r0,c0) = source row/col within the unit.
  uint32_t loc = (uint32_t)t * 16u;
  uint32_t g0 = loc ^ (((loc >> 9) & 1u) << 5);
  const int r0 = (int)(((g0 >> 10) >> 1) * 16 + ((g0 >> 6) & 15));  // 0..63
  const int c0 = (int)(((g0 >> 10) & 1) * 32 + ((g0 & 63) >> 1));   // 0..63

  // per-lane swizzled fragment read offset
  uint32_t lo_ = (uint32_t)((l & 15) * 64 + (l >> 4) * 16);
  const uint32_t lane_off = lo_ ^ (((lo_ >> 9) & 1u) << 5);
  const uint32_t aRegion = (uint32_t)(wr >> 7) * 16384u;
  const uint32_t smem_base = (uint32_t)(size_t)&smem_[0];
  const uint32_t aBase = smem_base + aRegion + lane_off;  // + parity + quad*4096

  // per-n B fragment base addresses (row = wc + n*16 within B panel)
  uint32_t bA[WN];
#pragma unroll
  for (int n = 0; n < WN; ++n) {
    const uint32_t row = (uint32_t)(wc + n * 16);
    bA[n] = smem_base + 32768u + (row >> 6) * 8192u + ((row & 63u) >> 4) * 2048u + lane_off;
  }

  // stage one 64-row unit of tile `tile` into parity (tile&1)
  auto STAGE1 = [&](const bf16* mat, int unit, int tile, uint32_t isB) {
    uint32_t dst = (uint32_t)(tile & 1) * PARB + isB + (uint32_t)unit * 8192u + (uint32_t)t * 16u;
    const bf16* src = mat + (long)(unit * 64 + r0) * K + tile * 64 + c0;
    GLOAD16(src, smem_ + (dst >> 1));
  };

  f32x4 acc[8][WN] = {};

  // ---- prologue: A(0) + B(0) into parity 0 (one-time full drain)
  STAGE1(Ab, 0, 0, 0u); STAGE1(Ab, 1, 0, 0u); STAGE1(Ab, 2, 0, 0u); STAGE1(Ab, 3, 0, 0u);
#pragma unroll
  for (int u = 0; u < WN; ++u) STAGE1(Bb, u, 0, 32768u);
  SB();
  WAIT_VMN(0);
  __builtin_amdgcn_s_barrier();

  // MFMA for output quad Q (acc rows Q*2, Q*2+1) using aF slot S
#define MFMAQ(Q, S)                                                                  \
  _Pragma("unroll") for (int mi = 0; mi < 2; ++mi)                                   \
  _Pragma("unroll") for (int n = 0; n < WN; ++n)                                     \
  _Pragma("unroll") for (int kk = 0; kk < 2; ++kk)                                   \
    acc[(Q) * 2 + mi][n] = __builtin_amdgcn_mfma_f32_16x16x32_bf16(                  \
        __builtin_bit_cast(bf16x8, aF[S][mi][kk]), __builtin_bit_cast(bf16x8, bF[n][kk]), \
        acc[(Q) * 2 + mi][n], 0, 0, 0);

  for (int T = 0; T < NT; ++T) {
    const uint32_t pb = (uint32_t)(T & 1) * PARB;
    const uint32_t aA = aBase + pb;
    f32x4 bF[WN][2];
    f32x4 aF[2][2][2];  // [slot][mi][kk]

    // ---- top: issue B(T+1) + A units {0,2} (phase-A readers' units) ----
    if (T + 1 < NT) {
#pragma unroll
      for (int u = 0; u < WN; ++u) STAGE1(Bb, u, T + 1, 32768u);
      STAGE1(Ab, 0, T + 1, 0u); STAGE1(Ab, 2, T + 1, 0u);
    }

    // ---- phase A: issue bF(2WN) + aF q0(4) + q1(4); data landed last tile ----
#pragma unroll
    for (int n = 0; n < WN; ++n) {
      DSR(bF[n][0], bA[n] + pb, "0");
      DSR(bF[n][1], bA[n] + pb, "1024");
    }
    DSR(aF[0][0][0], aA, "0");    DSR(aF[0][0][1], aA, "1024");
    DSR(aF[0][1][0], aA, "2048"); DSR(aF[0][1][1], aA, "3072");
    DSR(aF[1][0][0], aA, "4096"); DSR(aF[1][0][1], aA, "5120");
    DSR(aF[1][1][0], aA, "6144"); DSR(aF[1][1][1], aA, "7168");
    WAIT_LGKM4();   // bF + q0 landed; q1 (4 reads) in flight
    SB();           // rule #18: keep MFMA below the wait
    __builtin_amdgcn_s_setprio(1);
    MFMAQ(0, 0)
    __builtin_amdgcn_s_setprio(0);
    WAIT_LGKM0();   // q1 landed
    SB();
    __builtin_amdgcn_s_setprio(1);
    MFMAQ(1, 1)
    __builtin_amdgcn_s_setprio(0);

    // ---- mid: issue A units {1,3} of T+1 (phase-B readers' units) ----
    if (T + 1 < NT) { STAGE1(Ab, 1, T + 1, 0u); STAGE1(Ab, 3, T + 1, 0u); }

    // ---- mid wait: A1,A3(T) landed (issued mid of T-1; 1-tile cover).
    SB();
    if (T + 1 < NT) {
      if constexpr (WN == 2) { WAIT_VMN(6); } else { WAIT_VMN(8); }
    } else {
      WAIT_VMN(0);
    }
    __builtin_amdgcn_s_barrier();

    // ---- phase B: issue aF q2(4) + q3(4), reuse slots ----
    DSR(aF[0][0][0], aA, "8192");  DSR(aF[0][0][1], aA, "9216");
    DSR(aF[0][1][0], aA, "10240"); DSR(aF[0][1][1], aA, "11264");
    DSR(aF[1][0][0], aA, "12288"); DSR(aF[1][0][1], aA, "13312");
    DSR(aF[1][1][0], aA, "14336"); DSR(aF[1][1][1], aA, "15360");
    WAIT_LGKM4();   // q2 landed; q3 in flight
    SB();
    __builtin_amdgcn_s_setprio(1);
    MFMAQ(2, 0)
    __builtin_amdgcn_s_setprio(0);
    WAIT_LGKM0();   // q3 landed
    SB();
    __builtin_amdgcn_s_setprio(1);
    MFMAQ(3, 1)
    __builtin_amdgcn_s_setprio(0);

    // ---- boundary: B,A0,A2(T+1) landed; A1,A3(T+1) STAY IN FLIGHT ----
    SB();
    if (T + 1 < NT) { WAIT_VMN(2); } else { WAIT_VMN(0); }
    __builtin_amdgcn_s_barrier();
  }
#undef MFMAQ

  if constexpr (EPI == 4) {
    // ---- V-proj epilogue: transpose 256s x 128e block output through LDS,
    // then coalesced Vt stores. LDS parity buffers are dead (last boundary
    // barrier passed). Row stride 264 elems: rows 16B-aligned, banks spread.
    constexpr int STR = 264;  // elems per e-row (128 rows x 264 x 2B = 66KB < 96KB)
#pragma unroll
    for (int m = 0; m < 8; ++m)
#pragma unroll
      for (int n = 0; n < WN; ++n) {
        const int e = wc + n * 16 + (l & 15);
        const int s = wr + (l >> 4) * 4 + m * 16;
        ushort4 pk;
        pk.x = __builtin_bit_cast(unsigned short, (bf16)(acc[m][n][0] * alpha));
        pk.y = __builtin_bit_cast(unsigned short, (bf16)(acc[m][n][1] * alpha));
        pk.z = __builtin_bit_cast(unsigned short, (bf16)(acc[m][n][2] * alpha));
        pk.w = __builtin_bit_cast(unsigned short, (bf16)(acc[m][n][3] * alpha));
        *reinterpret_cast<ushort4*>(&smem_[e * STR + s]) = pk;  // 8B, aligned
      }
    __syncthreads();
    // rows of Vt: e-row = 256 bf16 = 32 chunks of 16B; 4 threads/row.
    bf16* Vt = (bf16*)Cp;
    const int bq = by >> 3;             // batch (by*256 / 2048)
    const int sbase = (by & 7) * 256;   // s offset within batch
    const int e0 = t >> 2;              // 0..127
#pragma unroll
    for (int it = 0; it < 8; ++it) {
      const int c = (t & 3) + it * 4;   // chunk index 0..31
      uint4 v = *reinterpret_cast<const uint4*>(&smem_[e0 * STR + c * 8]);
      *reinterpret_cast<uint4*>(
          &Vt[(long)bq * 2097152 + (long)(bx * BN + e0) * 2048 + sbase + c * 8]) = v;
    }
    return;
  }

  // ---- generic epilogue: C/D layout col = lane&15, row = (lane>>4)*4 + i
  const int orow0 = by * 256 + wr + (l >> 4) * 4;
  const int ocol0 = bx * BN + wc + (l & 15);
#pragma unroll
  for (int m = 0; m < 8; ++m)
#pragma unroll
    for (int n = 0; n < WN; ++n)
#pragma unroll
      for (int i = 0; i < 4; ++i) {
        const long r = orow0 + m * 16 + i;
        const long c = ocol0 + n * 16;
        const float v = acc[m][n][i] * alpha;
        if constexpr (EPI == 0) {
          ((bf16*)Cp)[z * sC + r * ldc + c] = (bf16)v;
        } else if constexpr (EPI == 2) {
          ((float*)Cp)[r * ldc + c] = v;
        } else if constexpr (EPI == 5) {
          // QK-proj route: c<1024 -> Q, else K  (rows r = b*2048+s)
          bf16* Qb = (bf16*)Cp;
          bf16* Kb = Qb + 8388608;  // 8192*1024
          if (c < 1024) Qb[r * 1024 + c] = (bf16)v;
          else Kb[r * 1024 + (c - 1024)] = (bf16)v;
        }
      }
}

// ---------------- row softmax, in place, rows of 2048 bf16 ----------------
__global__ __launch_bounds__(256) void softmax_rows(bf16* __restrict__ P) {
  const long row = blockIdx.x;
  bf16* p = P + row * 2048;
  const int t = threadIdx.x;
  const int lane = t & 63;
  const int wave = t >> 6;

  u16x8 raw = *reinterpret_cast<const u16x8*>(p + t * 8);
  float v[8];
#pragma unroll
  for (int j = 0; j < 8; ++j) {
    uint32_t bits = ((uint32_t)raw[j]) << 16;
    v[j] = __builtin_bit_cast(float, bits);
  }
  float m = v[0];
#pragma unroll
  for (int j = 1; j < 8; ++j) m = fmaxf(m, v[j]);
#pragma unroll
  for (int off = 32; off > 0; off >>= 1) m = fmaxf(m, __shfl_xor(m, off, 64));
  __shared__ float redm[4];
  __shared__ float reds[4];
  if (lane == 0) redm[wave] = m;
  __syncthreads();
  m = fmaxf(fmaxf(redm[0], redm[1]), fmaxf(redm[2], redm[3]));

  float s = 0.f;
#pragma unroll
  for (int j = 0; j < 8; ++j) {
    v[j] = __expf(v[j] - m);
    s += v[j];
  }
#pragma unroll
  for (int off = 32; off > 0; off >>= 1) s += __shfl_xor(s, off, 64);
  if (lane == 0) reds[wave] = s;
  __syncthreads();
  s = reds[0] + reds[1] + reds[2] + reds[3];
  const float inv = 1.f / s;

  u16x8 o;
#pragma unroll
  for (int j = 0; j < 8; ++j) o[j] = __builtin_bit_cast(unsigned short, (bf16)(v[j] * inv));
  *reinterpret_cast<u16x8*>(p + t * 8) = o;
}

// ---------------- launch ----------------
extern "C" void kernel_launch(void* const* d_in, const int* in_sizes, int n_in,
                              void* d_out, int out_size, void* d_ws, size_t ws_size,
                              hipStream_t stream) {
  const float* q = (const float*)d_in[0];
  const float* wq = (const float*)d_in[1];
  const float* wk = (const float*)d_in[2];
  const float* wv = (const float*)d_in[3];
  const float* wo = (const float*)d_in[4];
  float* out = (float*)d_out;

  constexpr int B = 4, S = 2048, D = 1024;
  constexpr long SD = (long)S * D;  // 2,097,152
  constexpr long SS = (long)S * S;  // 4,194,304
  constexpr long DD = (long)D * D;  // 1,048,576

  bf16* wsb = (bf16*)d_ws;
  bf16* qb = wsb;             // B*SD
  bf16* W3 = qb + B * SD;     // 3*DD  (wq;wk;wv stacked rows)
  bf16* wob = W3 + 3 * DD;    // DD
  bf16* Qb = wob + DD;        // B*SD
  bf16* Kb = Qb + B * SD;     // B*SD
  bf16* Vt = Kb + B * SD;     // B*SD, layout [B][D][S]
  bf16* P = Vt + B * SD;      // B*SS
  bf16* X = P + B * SS;       // B*SD, layout [B][D][S] == bugged buffer

  cvt_all<<<3072, 256, 0, stream>>>(q, wq, wk, wv, wo, qb, W3, wob);

  // QK-proj: [8192x1024] @ [2048x1024]^T -> Qb,Kb. WN=4, 256 blocks = 1/CU.
  g256<5, 4><<<dim3(8, 32, 1), 512, 0, stream>>>(qb, W3, Qb, D, 1.f, 0, 0, 0, 0);
  // V-proj: [8192x1024] @ [1024x1024]^T -> Vt via LDS-transpose epilogue.
  g256<4, 2><<<dim3(8, 32, 1), 512, 0, stream>>>(qb, W3 + 2 * DD, Vt, D, 1.f, 0, 0, 0, 0);
  // scores: P[b][i][j] = Q.K/8  (per batch 2048x2048, K=1024), 256 blocks = 1/CU
  g256<0, 4><<<dim3(8, 8, B), 512, 0, stream>>>(Qb, Kb, P, D, 0.125f, SD, SD, SS, S);
  softmax_rows<<<B * S, 256, 0, stream>>>(P);
  // PV as Xt = Vt @ P^T (M=1024, N=2048, K=2048): 256x128 tile, 256 blocks = 1/CU
  g256<0, 2><<<dim3(16, 4, B), 512, 0, stream>>>(Vt, P, X, S, 1.f, SD, SS, SD, S);
  // out = Xflat[8192x1024] @ wo^T -> f32: 256x128, 256 blocks = 1/CU
  g256<2, 2><<<dim3(8, 32, 1), 512, 0, stream>>>(X, wob, out, D, 1.f, 0, 0, 0, D);
}